// Round 4
// baseline (48.723 us; speedup 1.0000x reference)
//
#include <hip/hip_runtime.h>
#include <stdint.h>

#define AS_G __attribute__((address_space(1)))
#define AS_L __attribute__((address_space(3)))

typedef __bf16 bf16x8 __attribute__((ext_vector_type(8)));
typedef float  f32x4  __attribute__((ext_vector_type(4)));

static constexpr int NIMG = 16, CIN = 128, H = 64, W = 64, OCH = 128;
static constexpr int HO = 62, WO = 62;
static constexpr int PIX = HO * WO;            // 3844
static constexpr int M_TOT = NIMG * PIX;       // 61504
static constexpr int K_TOT = CIN * 9;          // 1152
static constexpr int BM = 64, BK = 64;
static constexpr int KSTEPS = K_TOT / BK;      // 18
// LDS: two buffers of 24 KB each: A (8 KB) at +0, B (16 KB) at +8192
static constexpr int BUFB = 24576;

__device__ __forceinline__ unsigned short f2bf(float f) {
    union { float f; uint32_t u; } v; v.f = f;
    uint32_t u = v.u;
    return (unsigned short)((u + 0x7FFFu + ((u >> 16) & 1u)) >> 16);
}

// Fused prep: blocks [0,1024): NCHW fp32 -> NHWC bf16; rest: weight prep.
__global__ __launch_bounds__(256) void prep_kernel(const float* __restrict__ x,
                                                   const float* __restrict__ wsrc,
                                                   unsigned short* __restrict__ xt,
                                                   unsigned short* __restrict__ bpd) {
    __shared__ float lds[CIN][W + 4];
    if (blockIdx.x < NIMG * H) {
        const int n   = blockIdx.x >> 6;
        const int h   = blockIdx.x & 63;
        const int tid = threadIdx.x;
        {
            const int c  = tid >> 1;
            const int w0 = (tid & 1) * 32;
            const float* src = x + (((size_t)(n * CIN + c) * H + h) * W + w0);
            #pragma unroll
            for (int j = 0; j < 8; ++j) {
                float4 v = *reinterpret_cast<const float4*>(src + j * 4);
                *reinterpret_cast<float4*>(&lds[c][w0 + j * 4]) = v;
            }
        }
        __syncthreads();
        {
            const int w  = tid >> 2;
            const int c0 = (tid & 3) * 32;
            unsigned short* dst = xt + (((size_t)(n * H + h) * W + w) * CIN + c0);
            uint32_t pk[16];
            #pragma unroll
            for (int j = 0; j < 16; ++j) {
                uint32_t lo = f2bf(lds[c0 + 2 * j][w]);
                uint32_t hi = f2bf(lds[c0 + 2 * j + 1][w]);
                pk[j] = lo | (hi << 16);
            }
            #pragma unroll
            for (int j = 0; j < 4; ++j) {
                *reinterpret_cast<uint4*>(dst + j * 8) =
                    make_uint4(pk[4 * j], pk[4 * j + 1], pk[4 * j + 2], pk[4 * j + 3]);
            }
        }
    } else {
        int tid = (blockIdx.x - NIMG * H) * 256 + threadIdx.x;
        if (tid < OCH * K_TOT) {
            int o  = tid / K_TOT;
            int kp = tid - o * K_TOT;   // kp = t*128 + c
            int t  = kp >> 7;
            int c  = kp & 127;
            bpd[tid] = f2bf(wsrc[o * K_TOT + c * 9 + t]);
        }
    }
}

// Implicit-GEMM conv: C[m][o] = sum_k A[m][k]*W[o][k], m=(n,y,x), k=(t,c)
// 2-phase schedule: STAGE(t+1) -> compute(t) -> sync. One barrier per K-step;
// prefetch latency hides under the 16-MFMA compute phase.
// mfma(bfr, af, acc): D rows = o, D cols = m -> coalesced stores.
__global__ __launch_bounds__(256) void gemm_kernel(const unsigned short* __restrict__ xt,
                                                   const unsigned short* __restrict__ bp,
                                                   const float* __restrict__ bias,
                                                   float* __restrict__ out) {
    __shared__ alignas(16) char lds[2 * BUFB];   // 48 KB -> 3 blocks/CU
    const int tid  = threadIdx.x;
    const int wv   = tid >> 6;
    const int lane = tid & 63;
    const int m0   = blockIdx.x * BM;   // 961*64 == M_TOT exactly: no bounds checks

    // staging: slot s covers bytes [s*16,s*16+16); row = s>>3 (8 slots / 128B row)
    // phys_byte = row*128 + (colbyte ^ ((row&7)<<4)); row&7 == lane>>3:
    const int csel = ((lane & 7) ^ (lane >> 3)) * 8;   // source col offset, elems
    int aBase[2], bBase[4];
    #pragma unroll
    for (int i = 0; i < 2; ++i) {
        int row = (wv * 2 + i) * 8 + (lane >> 3);      // m-row 0..63
        int m = m0 + row;
        int n  = m / PIX;
        int r  = m - n * PIX;
        int y  = r / WO;
        int xx = r - y * WO;
        aBase[i] = ((n * H + y) * W + xx) * CIN;       // NHWC elem index, tap 0
    }
    #pragma unroll
    for (int i = 0; i < 4; ++i)
        bBase[i] = ((wv * 4 + i) * 8 + (lane >> 3)) * K_TOT;   // o-row 0..127

    auto stage = [&](int buf, int step) {
        const int t  = step >> 1;
        const int c0 = (step & 1) * 64;
        const int tapoff = (t / 3) * (W * CIN) + (t % 3) * CIN + c0;
        const int kb = step * BK;
        char* dst = lds + buf * BUFB;
        #pragma unroll
        for (int i = 0; i < 2; ++i)
            __builtin_amdgcn_global_load_lds(
                (AS_G unsigned int*)(xt + aBase[i] + tapoff + csel),
                (AS_L unsigned int*)(dst + (wv * 2 + i) * 1024), 16, 0, 0);
        #pragma unroll
        for (int i = 0; i < 4; ++i)
            __builtin_amdgcn_global_load_lds(
                (AS_G unsigned int*)(bp + bBase[i] + kb + csel),
                (AS_L unsigned int*)(dst + 8192 + (wv * 4 + i) * 1024), 16, 0, 0);
    };

    // compute-side fragment addresses
    const int wr = wv >> 1, wc = wv & 1;               // wave tile: m 32, o 64
    const int lr = lane & 15, lq = lane >> 4;
    const int aRow = (wr * 32 + lr) * 128;             // byte offset of m-row
    const int bRow = (wc * 64 + lr) * 128;             // byte offset of o-row
    int colx[2];
    #pragma unroll
    for (int ks = 0; ks < 2; ++ks)
        colx[ks] = (ks * 64 + lq * 16) ^ ((lane & 7) << 4);

    f32x4 acc[2][4];
    #pragma unroll
    for (int a = 0; a < 2; ++a)
        #pragma unroll
        for (int b = 0; b < 4; ++b)
            acc[a][b] = (f32x4){0.f, 0.f, 0.f, 0.f};

    stage(0, 0);
    __syncthreads();

    #pragma unroll 2
    for (int step = 0; step < KSTEPS; ++step) {
        const int buf = step & 1;
        if (step + 1 < KSTEPS) stage(buf ^ 1, step + 1);   // prefetch next tile
        const char* base = lds + buf * BUFB;
        #pragma unroll
        for (int ks = 0; ks < 2; ++ks) {
            bf16x8 af[2], bfr[4];
            #pragma unroll
            for (int mi = 0; mi < 2; ++mi)
                af[mi] = *(const bf16x8*)(base + aRow + mi * 2048 + colx[ks]);
            #pragma unroll
            for (int ni = 0; ni < 4; ++ni)
                bfr[ni] = *(const bf16x8*)(base + 8192 + bRow + ni * 2048 + colx[ks]);
            #pragma unroll
            for (int mi = 0; mi < 2; ++mi)
                #pragma unroll
                for (int ni = 0; ni < 4; ++ni)
                    acc[mi][ni] = __builtin_amdgcn_mfma_f32_16x16x32_bf16(
                        bfr[ni], af[mi], acc[mi][ni], 0, 0, 0);   // D rows=o, cols=m
        }
        __syncthreads();   // drains the prefetch (hidden under compute) + rendezvous
    }

    // epilogue: D col = lane&15 = m (consecutive!), row = (lane>>4)*4+j = o
    f32x4 bv[4];
    #pragma unroll
    for (int ni = 0; ni < 4; ++ni)
        bv[ni] = *(const f32x4*)(bias + wc * 64 + ni * 16 + lq * 4);
    #pragma unroll
    for (int mi = 0; mi < 2; ++mi) {
        int m = m0 + wr * 32 + mi * 16 + lr;
        int n  = m / PIX;
        int r  = m - n * PIX;
        int y  = r / WO;
        int xx = r - y * WO;
        float* ob = out + (size_t)n * OCH * PIX + y * WO + xx;
        #pragma unroll
        for (int ni = 0; ni < 4; ++ni)
            #pragma unroll
            for (int j = 0; j < 4; ++j) {
                int o = wc * 64 + ni * 16 + lq * 4 + j;
                ob[(size_t)o * PIX] = acc[mi][ni][j] + bv[ni][j];
            }
    }
}

extern "C" void kernel_launch(void* const* d_in, const int* in_sizes, int n_in,
                              void* d_out, int out_size, void* d_ws, size_t ws_size,
                              hipStream_t stream) {
    const float* x    = (const float*)d_in[0];
    const float* wsrc = (const float*)d_in[1];
    const float* bias = (const float*)d_in[2];
    float* out = (float*)d_out;
    unsigned short* xt = (unsigned short*)d_ws;                 // 16 MiB NHWC bf16
    unsigned short* bp = xt + (size_t)NIMG * H * W * CIN;       // 288 KiB weights
    prep_kernel<<<dim3(NIMG * H + (OCH * K_TOT + 255) / 256), dim3(256), 0, stream>>>(
        x, wsrc, xt, bp);
    gemm_kernel<<<dim3(M_TOT / BM), dim3(256), 0, stream>>>(xt, bp, bias, out);
}

// Round 5
// 47.365 us; speedup vs baseline: 1.0287x; 1.0287x over previous
//
#include <hip/hip_runtime.h>
#include <stdint.h>

#define AS_G __attribute__((address_space(1)))
#define AS_L __attribute__((address_space(3)))

typedef __bf16 bf16x8 __attribute__((ext_vector_type(8)));
typedef float  f32x4  __attribute__((ext_vector_type(4)));

static constexpr int NIMG = 16, CIN = 128, H = 64, W = 64, OCH = 128;
static constexpr int HO = 62, WO = 62;
static constexpr int PIX = HO * WO;            // 3844
static constexpr int M_TOT = NIMG * PIX;       // 61504
static constexpr int K_TOT = CIN * 9;          // 1152
static constexpr int BM = 128;                 // block m-tile; wave = 32m x 128o
static constexpr int NCHUNK = 9;               // one 3x3 tap per chunk (128 k each)
static constexpr int GRID = (M_TOT + BM - 1) / BM;   // 481

__device__ __forceinline__ unsigned short f2bf(float f) {
    union { float f; uint32_t u; } v; v.f = f;
    uint32_t u = v.u;
    return (unsigned short)((u + 0x7FFFu + ((u >> 16) & 1u)) >> 16);
}

// Fused prep: blocks [0,1024): NCHW fp32 -> NHWC bf16; rest: weight prep.
__global__ __launch_bounds__(256) void prep_kernel(const float* __restrict__ x,
                                                   const float* __restrict__ wsrc,
                                                   unsigned short* __restrict__ xt,
                                                   unsigned short* __restrict__ bpd) {
    __shared__ float lds[CIN][W + 4];
    if (blockIdx.x < NIMG * H) {
        const int n   = blockIdx.x >> 6;
        const int h   = blockIdx.x & 63;
        const int tid = threadIdx.x;
        {
            const int c  = tid >> 1;
            const int w0 = (tid & 1) * 32;
            const float* src = x + (((size_t)(n * CIN + c) * H + h) * W + w0);
            #pragma unroll
            for (int j = 0; j < 8; ++j) {
                float4 v = *reinterpret_cast<const float4*>(src + j * 4);
                *reinterpret_cast<float4*>(&lds[c][w0 + j * 4]) = v;
            }
        }
        __syncthreads();
        {
            const int w  = tid >> 2;
            const int c0 = (tid & 3) * 32;
            unsigned short* dst = xt + (((size_t)(n * H + h) * W + w) * CIN + c0);
            uint32_t pk[16];
            #pragma unroll
            for (int j = 0; j < 16; ++j) {
                uint32_t lo = f2bf(lds[c0 + 2 * j][w]);
                uint32_t hi = f2bf(lds[c0 + 2 * j + 1][w]);
                pk[j] = lo | (hi << 16);
            }
            #pragma unroll
            for (int j = 0; j < 4; ++j) {
                *reinterpret_cast<uint4*>(dst + j * 8) =
                    make_uint4(pk[4 * j], pk[4 * j + 1], pk[4 * j + 2], pk[4 * j + 3]);
            }
        }
    } else {
        int tid = (blockIdx.x - NIMG * H) * 256 + threadIdx.x;
        if (tid < OCH * K_TOT) {
            int o  = tid / K_TOT;
            int kp = tid - o * K_TOT;   // kp = t*128 + c
            int t  = kp >> 7;
            int c  = kp & 127;
            bpd[tid] = f2bf(wsrc[o * K_TOT + c * 9 + t]);
        }
    }
}

// Implicit-GEMM conv. Weights (one tap = 128o x 128c = 32 KB) double-buffered
// in LDS, XOR-swizzled; activations loaded DIRECTLY global->VGPR (NHWC makes
// each B-operand fragment a 16B contiguous channel run -> no A staging, no
// A barriers). 9 chunks -> 9 barriers per block total.
// mfma(wf, af, acc): D rows = o, D cols = m -> coalesced stores.
__global__ __launch_bounds__(256) void gemm_kernel(const unsigned short* __restrict__ xt,
                                                   const unsigned short* __restrict__ bp,
                                                   const float* __restrict__ bias,
                                                   float* __restrict__ out) {
    __shared__ alignas(16) char lds[2 * 32768];   // 64 KB -> 2 blocks/CU
    const int tid  = threadIdx.x;
    const int wv   = tid >> 6;
    const int lane = tid & 63;
    const int lr   = lane & 15, lq = lane >> 4;
    const int m0   = blockIdx.x * BM;

    // ---- B staging offsets: 8 slots/thread; slot s -> phys bytes [s*16,s*16+16)
    // row o = s>>4 (256 B rows), phys 16B-idx q = s&15; logical = q ^ (o&7) ----
    int bOff[8];
    #pragma unroll
    for (int p = 0; p < 8; ++p) {
        int s = (wv * 8 + p) * 64 + lane;
        int o = s >> 4, q = s & 15;
        bOff[p] = o * K_TOT + ((q ^ (o & 7)) * 8);
    }
    auto stageB = [&](int buf, int t) {
        const unsigned short* src = bp + t * 128;
        char* dst = lds + buf * 32768;
        #pragma unroll
        for (int p = 0; p < 8; ++p)
            __builtin_amdgcn_global_load_lds(
                (AS_G unsigned int*)(src + bOff[p]),
                (AS_L unsigned int*)(dst + (wv * 8 + p) * 1024), 16, 0, 0);
    };

    // ---- activation pixel bases (tap 0) + store bases, per m-subtile ----
    int base0[2], ybase[2];
    bool valid[2];
    #pragma unroll
    for (int mi = 0; mi < 2; ++mi) {
        int m = m0 + wv * 32 + mi * 16 + lr;
        valid[mi] = (m < M_TOT);
        if (m >= M_TOT) m = M_TOT - 1;
        int n  = m / PIX;
        int r  = m - n * PIX;
        int y  = r / WO;
        int xx = r - y * WO;
        base0[mi] = ((n * H + y) * W + xx) * CIN + lq * 8;   // elems, + c-group
        ybase[mi] = n * OCH * PIX + y * WO + xx;             // out elems (o=0)
    }

    f32x4 acc[2][8];
    #pragma unroll
    for (int a = 0; a < 2; ++a)
        #pragma unroll
        for (int b = 0; b < 8; ++b)
            acc[a][b] = (f32x4){0.f, 0.f, 0.f, 0.f};

    stageB(0, 0);
    __syncthreads();

    const int wxor = (lr & 7) << 4;     // o&7 == lr&7 for all 8 o-subtiles
    for (int t = 0; t < NCHUNK; ++t) {
        if (t + 1 < NCHUNK) stageB((t & 1) ^ 1, t + 1);     // prefetch next tap
        const char* wb = lds + (t & 1) * 32768;
        const int kh = t / 3, kw = t - kh * 3;
        const int tapoff = (kh * W + kw) * CIN;             // elems
        #pragma unroll
        for (int ks = 0; ks < 4; ++ks) {                    // 32-k slices
            bf16x8 af[2], wf[8];
            #pragma unroll
            for (int mi = 0; mi < 2; ++mi)
                af[mi] = *(const bf16x8*)(xt + base0[mi] + tapoff + ks * 32);
            const int colw = (ks * 64 + lq * 16) ^ wxor;
            #pragma unroll
            for (int ni = 0; ni < 8; ++ni)
                wf[ni] = *(const bf16x8*)(wb + ni * 4096 + lr * 256 + colw);
            #pragma unroll
            for (int mi = 0; mi < 2; ++mi)
                #pragma unroll
                for (int ni = 0; ni < 8; ++ni)
                    acc[mi][ni] = __builtin_amdgcn_mfma_f32_16x16x32_bf16(
                        wf[ni], af[mi], acc[mi][ni], 0, 0, 0);
        }
        __syncthreads();   // drains prefetch (hidden under 64 MFMA) + rendezvous
    }

    // ---- epilogue: D col = lane&15 = m (consecutive x), row = lq*4+j = o ----
    #pragma unroll
    for (int mi = 0; mi < 2; ++mi) {
        if (valid[mi]) {
            float* ob = out + ybase[mi];
            #pragma unroll
            for (int ni = 0; ni < 8; ++ni) {
                f32x4 bv = *(const f32x4*)(bias + ni * 16 + lq * 4);
                #pragma unroll
                for (int j = 0; j < 4; ++j)
                    ob[(size_t)(ni * 16 + lq * 4 + j) * PIX] = acc[mi][ni][j] + bv[j];
            }
        }
    }
}

extern "C" void kernel_launch(void* const* d_in, const int* in_sizes, int n_in,
                              void* d_out, int out_size, void* d_ws, size_t ws_size,
                              hipStream_t stream) {
    const float* x    = (const float*)d_in[0];
    const float* wsrc = (const float*)d_in[1];
    const float* bias = (const float*)d_in[2];
    float* out = (float*)d_out;
    unsigned short* xt = (unsigned short*)d_ws;                 // 16 MiB NHWC bf16
    unsigned short* bp = xt + (size_t)NIMG * H * W * CIN;       // 288 KiB weights
    prep_kernel<<<dim3(NIMG * H + (OCH * K_TOT + 255) / 256), dim3(256), 0, stream>>>(
        x, wsrc, xt, bp);
    gemm_kernel<<<dim3(GRID), dim3(256), 0, stream>>>(xt, bp, bias, out);
}

// Round 6
// 43.530 us; speedup vs baseline: 1.1193x; 1.0881x over previous
//
#include <hip/hip_runtime.h>
#include <stdint.h>

#define AS_G __attribute__((address_space(1)))
#define AS_L __attribute__((address_space(3)))

typedef __bf16 bf16x8 __attribute__((ext_vector_type(8)));
typedef float  f32x4  __attribute__((ext_vector_type(4)));

static constexpr int NIMG = 16, CIN = 128, H = 64, W = 64, OCH = 128;
static constexpr int HO = 62, WO = 62;
static constexpr int PIX = HO * WO;            // 3844
static constexpr int M_TOT = NIMG * PIX;       // 61504
static constexpr int K_TOT = CIN * 9;          // 1152
static constexpr int BM = 64, BK = 64;
static constexpr int KSTEPS = K_TOT / BK;      // 18
static constexpr int NWG = M_TOT / BM;         // 961 blocks
// bijective XCD swizzle (m204): 961 = 8*120 + 1 -> q=120, r=1

__device__ __forceinline__ unsigned short f2bf(float f) {
    union { float f; uint32_t u; } v; v.f = f;
    uint32_t u = v.u;
    return (unsigned short)((u + 0x7FFFu + ((u >> 16) & 1u)) >> 16);
}

// Fused prep: blocks [0,1024): NCHW fp32 -> NHWC bf16; rest: weight prep.
__global__ __launch_bounds__(256) void prep_kernel(const float* __restrict__ x,
                                                   const float* __restrict__ wsrc,
                                                   unsigned short* __restrict__ xt,
                                                   unsigned short* __restrict__ bpd) {
    __shared__ float lds[CIN][W + 4];
    if (blockIdx.x < NIMG * H) {
        const int n   = blockIdx.x >> 6;
        const int h   = blockIdx.x & 63;
        const int tid = threadIdx.x;
        {
            const int c  = tid >> 1;
            const int w0 = (tid & 1) * 32;
            const float* src = x + (((size_t)(n * CIN + c) * H + h) * W + w0);
            #pragma unroll
            for (int j = 0; j < 8; ++j) {
                float4 v = *reinterpret_cast<const float4*>(src + j * 4);
                *reinterpret_cast<float4*>(&lds[c][w0 + j * 4]) = v;
            }
        }
        __syncthreads();
        {
            const int w  = tid >> 2;
            const int c0 = (tid & 3) * 32;
            unsigned short* dst = xt + (((size_t)(n * H + h) * W + w) * CIN + c0);
            uint32_t pk[16];
            #pragma unroll
            for (int j = 0; j < 16; ++j) {
                uint32_t lo = f2bf(lds[c0 + 2 * j][w]);
                uint32_t hi = f2bf(lds[c0 + 2 * j + 1][w]);
                pk[j] = lo | (hi << 16);
            }
            #pragma unroll
            for (int j = 0; j < 4; ++j) {
                *reinterpret_cast<uint4*>(dst + j * 8) =
                    make_uint4(pk[4 * j], pk[4 * j + 1], pk[4 * j + 2], pk[4 * j + 3]);
            }
        }
    } else {
        int tid = (blockIdx.x - NIMG * H) * 256 + threadIdx.x;
        if (tid < OCH * K_TOT) {
            int o  = tid / K_TOT;
            int kp = tid - o * K_TOT;   // kp = t*128 + c
            int t  = kp >> 7;
            int c  = kp & 127;
            bpd[tid] = f2bf(wsrc[o * K_TOT + c * 9 + t]);
        }
    }
}

// Implicit-GEMM conv: C[m][o] = sum_k A[m][k]*W[o][k], m=(n,y,x), k=(t,c)
// Round-2 structure (measured best, 0 LDS conflicts) + XCD-aware bijective
// blockIdx swizzle: contiguous m-chunks per XCD so each XCD's A working set
// (~2 MB) fits its private 4 MB L2 -> staging loads become L2 hits.
// mfma(bfr, af, acc): D rows = o, D cols = m -> coalesced stores.
__global__ __launch_bounds__(256) void gemm_kernel(const unsigned short* __restrict__ xt,
                                                   const unsigned short* __restrict__ bp,
                                                   const float* __restrict__ bias,
                                                   float* __restrict__ out) {
    __shared__ alignas(16) unsigned short As[BM * BK];   // 8 KB, XOR-swizzled
    __shared__ alignas(16) unsigned short Bs[OCH * BK];  // 16 KB, XOR-swizzled
    const int tid  = threadIdx.x;
    const int wv   = tid >> 6;
    const int lane = tid & 63;

    // ---- bijective XCD swizzle (961 = 8*120+1: q=120, r=1) ----
    const int orig = blockIdx.x;
    const int xcd  = orig & 7;
    const int idx  = orig >> 3;
    const int wg   = (xcd == 0 ? 0 : 121 + (xcd - 1) * 120) + idx;
    const int m0   = wg * BM;

    // staging: slot s covers bytes [s*16,s*16+16); row = s>>3 (8 slots / 128B row)
    // phys_byte = row*128 + (colbyte ^ ((row&7)<<4)); row&7 == lane>>3:
    const int csel = ((lane & 7) ^ (lane >> 3)) * 8;   // source col offset, elems
    int aBase[2], bBase[4];
    #pragma unroll
    for (int i = 0; i < 2; ++i) {
        int row = (wv * 2 + i) * 8 + (lane >> 3);      // m-row 0..63
        int m = m0 + row;
        int n  = m / PIX;
        int r  = m - n * PIX;
        int y  = r / WO;
        int xx = r - y * WO;
        aBase[i] = ((n * H + y) * W + xx) * CIN;       // NHWC elem index, tap 0
    }
    #pragma unroll
    for (int i = 0; i < 4; ++i)
        bBase[i] = ((wv * 4 + i) * 8 + (lane >> 3)) * K_TOT;   // o-row 0..127

    // compute-side fragment addresses
    const int wr = wv >> 1, wc = wv & 1;               // wave tile: m 32, o 64
    const int lr = lane & 15, lq = lane >> 4;
    const int aRow = (wr * 32 + lr) * 128;             // byte offset of m-row
    const int bRow = (wc * 64 + lr) * 128;             // byte offset of o-row
    int colx[2];
    #pragma unroll
    for (int ks = 0; ks < 2; ++ks)
        colx[ks] = (ks * 64 + lq * 16) ^ ((lane & 7) << 4);

    f32x4 acc[2][4];
    #pragma unroll
    for (int a = 0; a < 2; ++a)
        #pragma unroll
        for (int b = 0; b < 4; ++b)
            acc[a][b] = (f32x4){0.f, 0.f, 0.f, 0.f};

    const char* AsB = (const char*)As;
    const char* BsB = (const char*)Bs;

    for (int step = 0; step < KSTEPS; ++step) {
        const int t  = step >> 1;
        const int c0 = (step & 1) * 64;
        const int tapoff = (t / 3) * (W * CIN) + (t % 3) * CIN + c0;
        const int kb = step * BK;
        #pragma unroll
        for (int i = 0; i < 2; ++i)
            __builtin_amdgcn_global_load_lds(
                (AS_G unsigned int*)(xt + aBase[i] + tapoff + csel),
                (AS_L unsigned int*)((char*)As + (wv * 2 + i) * 1024),
                16, 0, 0);
        #pragma unroll
        for (int i = 0; i < 4; ++i)
            __builtin_amdgcn_global_load_lds(
                (AS_G unsigned int*)(bp + bBase[i] + kb + csel),
                (AS_L unsigned int*)((char*)Bs + (wv * 4 + i) * 1024),
                16, 0, 0);
        __syncthreads();
        #pragma unroll
        for (int ks = 0; ks < 2; ++ks) {
            bf16x8 af[2], bfr[4];
            #pragma unroll
            for (int mi = 0; mi < 2; ++mi)
                af[mi] = *(const bf16x8*)(AsB + aRow + mi * 2048 + colx[ks]);
            #pragma unroll
            for (int ni = 0; ni < 4; ++ni)
                bfr[ni] = *(const bf16x8*)(BsB + bRow + ni * 2048 + colx[ks]);
            #pragma unroll
            for (int mi = 0; mi < 2; ++mi)
                #pragma unroll
                for (int ni = 0; ni < 4; ++ni)
                    acc[mi][ni] = __builtin_amdgcn_mfma_f32_16x16x32_bf16(
                        bfr[ni], af[mi], acc[mi][ni], 0, 0, 0);   // D rows=o, cols=m
        }
        __syncthreads();
    }

    // epilogue: D col = lane&15 = m (consecutive!), row = (lane>>4)*4+j = o
    f32x4 bv[4];
    #pragma unroll
    for (int ni = 0; ni < 4; ++ni)
        bv[ni] = *(const f32x4*)(bias + wc * 64 + ni * 16 + lq * 4);
    #pragma unroll
    for (int mi = 0; mi < 2; ++mi) {
        int m = m0 + wr * 32 + mi * 16 + lr;
        int n  = m / PIX;
        int r  = m - n * PIX;
        int y  = r / WO;
        int xx = r - y * WO;
        float* ob = out + (size_t)n * OCH * PIX + y * WO + xx;
        #pragma unroll
        for (int ni = 0; ni < 4; ++ni)
            #pragma unroll
            for (int j = 0; j < 4; ++j) {
                int o = wc * 64 + ni * 16 + lq * 4 + j;
                ob[(size_t)o * PIX] = acc[mi][ni][j] + bv[ni][j];
            }
    }
}

extern "C" void kernel_launch(void* const* d_in, const int* in_sizes, int n_in,
                              void* d_out, int out_size, void* d_ws, size_t ws_size,
                              hipStream_t stream) {
    const float* x    = (const float*)d_in[0];
    const float* wsrc = (const float*)d_in[1];
    const float* bias = (const float*)d_in[2];
    float* out = (float*)d_out;
    unsigned short* xt = (unsigned short*)d_ws;                 // 16 MiB NHWC bf16
    unsigned short* bp = xt + (size_t)NIMG * H * W * CIN;       // 288 KiB weights
    prep_kernel<<<dim3(NIMG * H + (OCH * K_TOT + 255) / 256), dim3(256), 0, stream>>>(
        x, wsrc, xt, bp);
    gemm_kernel<<<dim3(NWG), dim3(256), 0, stream>>>(xt, bp, bias, out);
}